// Round 9
// baseline (496.324 us; speedup 1.0000x reference)
//
#include <hip/hip_runtime.h>

// Problem constants: B=8, M=N=256, D=512
#define INFV 1.0e8f

// Raw HW transcendentals: v_exp_f32 is 2^x, v_log_f32 is log2(x).
#define EXP2F(x) __builtin_amdgcn_exp2f(x)
#define LOG2F(x) __builtin_amdgcn_logf(x)
#define MED3F(a,b,c) __builtin_amdgcn_fmed3f(a,b,c)

// LDS-only barrier: syncs the block's 4 waves without draining vmcnt, so
// global prefetch FIFO loads stay in flight across relay slots.
__device__ __forceinline__ void lds_barrier() {
  asm volatile("s_waitcnt lgkmcnt(0)\n\ts_barrier" ::: "memory");
}

// ---------------------------------------------------------------------------
// Kernel 1: inverse row norms.  rn = 1 / max(||row||, 1e-8)
// ---------------------------------------------------------------------------
__global__ void __launch_bounds__(256) norms_kernel(const float* __restrict__ x,
                                                    const float* __restrict__ y,
                                                    float* __restrict__ rnx,
                                                    float* __restrict__ rny) {
  int g = blockIdx.x * 4 + (threadIdx.x >> 6);
  int lane = threadIdx.x & 63;
  const float* src; float* dst; int row;
  if (g < 2048) { src = x; dst = rnx; row = g; }
  else          { src = y; dst = rny; row = g - 2048; }
  const float* p = src + (size_t)row * 512;
  float4 v0 = *(const float4*)(p + lane * 4);
  float4 v1 = *(const float4*)(p + 256 + lane * 4);
  float s = v0.x*v0.x + v0.y*v0.y + v0.z*v0.z + v0.w*v0.w
          + v1.x*v1.x + v1.y*v1.y + v1.z*v1.z + v1.w*v1.w;
#pragma unroll
  for (int o = 32; o > 0; o >>= 1) s += __shfl_xor(s, o, 64);
  if (lane == 0) dst[row] = 1.0f / fmaxf(sqrtf(s), 1e-8f);
}

// ---------------------------------------------------------------------------
// Kernel 2: cost GEMM -> ROW-MAJOR costR[b][m][n], PRE-SCALED by ig2=log2e/gv.
// ---------------------------------------------------------------------------
__global__ void __launch_bounds__(256) cost_gemm(const float* __restrict__ x,
                                                 const float* __restrict__ y,
                                                 const float* __restrict__ rnx,
                                                 const float* __restrict__ rny,
                                                 const float* __restrict__ gamma,
                                                 float* __restrict__ costR) {
  int b = blockIdx.z, mt = blockIdx.y, nt = blockIdx.x;
  int m0 = mt * 64, n0 = nt * 64;
  __shared__ float Xs[16][68];
  __shared__ float Ys[16][68];
  int tid = threadIdx.x;
  int row = tid >> 2, cq = tid & 3;
  int tx = tid & 15, ty = tid >> 4;
  const float* xb = x + ((size_t)b * 256 + m0) * 512;
  const float* yb = y + ((size_t)b * 256 + n0) * 512;
  float acc[4][4] = {};
  for (int k0 = 0; k0 < 512; k0 += 16) {
    float4 xv = *(const float4*)(xb + (size_t)row * 512 + k0 + cq * 4);
    float4 yv = *(const float4*)(yb + (size_t)row * 512 + k0 + cq * 4);
    __syncthreads();
    Xs[cq*4+0][row] = xv.x; Xs[cq*4+1][row] = xv.y;
    Xs[cq*4+2][row] = xv.z; Xs[cq*4+3][row] = xv.w;
    Ys[cq*4+0][row] = yv.x; Ys[cq*4+1][row] = yv.y;
    Ys[cq*4+2][row] = yv.z; Ys[cq*4+3][row] = yv.w;
    __syncthreads();
#pragma unroll
    for (int kk = 0; kk < 16; ++kk) {
      float4 av = *(const float4*)(&Xs[kk][ty * 4]);
      float4 bv = *(const float4*)(&Ys[kk][tx * 4]);
      float ar[4] = {av.x, av.y, av.z, av.w};
      float br[4] = {bv.x, bv.y, bv.z, bv.w};
#pragma unroll
      for (int r = 0; r < 4; ++r)
#pragma unroll
        for (int c = 0; c < 4; ++c)
          acc[r][c] += ar[r] * br[c];
    }
  }
  float gv = fmaxf(fabsf(gamma[0]), 1e-4f);
  float ig2 = 1.4426950408889634f / gv;
  float rx[4], ry[4];
#pragma unroll
  for (int r = 0; r < 4; ++r) rx[r] = rnx[b * 256 + m0 + ty * 4 + r];
#pragma unroll
  for (int c = 0; c < 4; ++c) ry[c] = rny[b * 256 + n0 + tx * 4 + c];
  float* cbb = costR + (size_t)b * 65536;
#pragma unroll
  for (int r = 0; r < 4; ++r) {
    int m = m0 + ty * 4 + r;
    float4 st = {(1.0f - acc[r][0] * rx[r] * ry[0]) * ig2,
                 (1.0f - acc[r][1] * rx[r] * ry[1]) * ig2,
                 (1.0f - acc[r][2] * rx[r] * ry[2]) * ig2,
                 (1.0f - acc[r][3] * rx[r] * ry[3]) * ig2};
    *(float4*)(cbb + (size_t)m * 256 + n0 + tx * 4) = st;
  }
}

// ---------------------------------------------------------------------------
// Kernel 3: forward soft-DTW -- 4-WAVE RELAY per batch.  Wave w owns rows
// 64w..64w+63, lane l owns row r=64w+l.  Slot s: lane processes column group
// g = s-64w-l (cols 4g..4g+3).  Row r-1 comes from shfl_up (in-wave) or the
// LDS ring (wave boundary, written one slot earlier by lane63 of wave w-1).
// q = R*(log2e/gv); cost pre-scaled.  Softmin: one exp2 arg is exactly 0, so
// s3 = 1 + exp2(mn-med) + exp2(mn-max) -- 3 transcendentals/cell, not 4.
// 321 lockstep slots, lgkm-only barrier each.
// ---------------------------------------------------------------------------
__global__ void __launch_bounds__(256, 1) fwd_kernel(const float* __restrict__ costR,
                                                     const float* __restrict__ gamma,
                                                     float* __restrict__ qR,
                                                     float* __restrict__ dist_out) {
  int b = blockIdx.x;
  int t = threadIdx.x, w = t >> 6, l = t & 63;
  int r = 64 * w + l;
  float gv = fmaxf(fabsf(gamma[0]), 1e-4f);
  float gl = gv * 0.6931471805599453f;   // R = q * gl
  const float* crow = costR + (size_t)b * 65536 + (size_t)r * 256;
  float* qrow = qR + (size_t)b * 65536 + (size_t)r * 256;
  __shared__ float ring[3][64][4];       // interface wave w -> w+1, per group
  float lprev = INFV;                                  // my row, col 4g-1
  float ucar = (w == 0 && l == 0) ? 0.0f : INFV;       // row r-1, col 4g-1
  float o0 = INFV, o1 = INFV, o2 = INFV, o3 = INFV;    // my last group's out
  int base = 64 * w, myoff = base + l;
  float A0[4], A1[4], A2[4];

  auto loadC = [&](int s, float* buf) {
    if ((unsigned)(s - base) > 126u) return;
    int g = s - myoff;
    g = g < 0 ? 0 : (g > 63 ? 63 : g);
    float4 v = *(const float4*)(crow + 4 * g);
    buf[0] = v.x; buf[1] = v.y; buf[2] = v.z; buf[3] = v.w;
  };
  auto body = [&](int s, const float* cc) {
    if ((unsigned)(s - base) <= 126u) {
      int g = s - myoff;
      bool act = (unsigned)g <= 63u;
      int gc = g < 0 ? 0 : (g > 63 ? 63 : g);
      float u0 = __shfl_up(o0, 1), u1 = __shfl_up(o1, 1),
            u2 = __shfl_up(o2, 1), u3 = __shfl_up(o3, 1);
      if (l == 0) {
        if (w == 0) { u0 = u1 = u2 = u3 = INFV; }
        else {
          float4 rv = *(const float4*)ring[w - 1][gc];
          u0 = rv.x; u1 = rv.y; u2 = rv.z; u3 = rv.w;
        }
      }
      float v0, v1, v2, v3;
      {
        float a = u0, bl = lprev, c = ucar;
        float mn = fminf(fminf(a, bl), c), md = MED3F(a, bl, c),
              mx = fmaxf(fmaxf(a, bl), c);
        v0 = cc[0] + (mn - LOG2F(1.0f + EXP2F(mn - md) + EXP2F(mn - mx)));
      }
      {
        float a = u1, bl = v0, c = u0;
        float mn = fminf(fminf(a, bl), c), md = MED3F(a, bl, c),
              mx = fmaxf(fmaxf(a, bl), c);
        v1 = cc[1] + (mn - LOG2F(1.0f + EXP2F(mn - md) + EXP2F(mn - mx)));
      }
      {
        float a = u2, bl = v1, c = u1;
        float mn = fminf(fminf(a, bl), c), md = MED3F(a, bl, c),
              mx = fmaxf(fmaxf(a, bl), c);
        v2 = cc[2] + (mn - LOG2F(1.0f + EXP2F(mn - md) + EXP2F(mn - mx)));
      }
      {
        float a = u3, bl = v2, c = u2;
        float mn = fminf(fminf(a, bl), c), md = MED3F(a, bl, c),
              mx = fmaxf(fmaxf(a, bl), c);
        v3 = cc[3] + (mn - LOG2F(1.0f + EXP2F(mn - md) + EXP2F(mn - mx)));
      }
      if (act) {
        float4 st = {v0, v1, v2, v3};
        *(float4*)(qrow + 4 * g) = st;
        o0 = v0; o1 = v1; o2 = v2; o3 = v3;
        lprev = v3; ucar = u3;
        if (l == 63 && w < 3) *(float4*)ring[w][g] = st;
        if (w == 3 && l == 63 && g == 63) dist_out[b] = v3 * gl;
      }
    }
    lds_barrier();
  };

  loadC(0, A0); loadC(1, A1); loadC(2, A2);
  for (int it = 0; it < 107; ++it) {   // 321 slots; last live slot = 318
    int s = it * 3;
    body(s + 0, A0); loadC(s + 3, A0);
    body(s + 1, A1); loadC(s + 4, A1);
    body(s + 2, A2); loadC(s + 5, A2);
  }
}

// ---------------------------------------------------------------------------
// Kernel 3.5: backward weights, one thread per cell, all row-major.
//   wd=exp2(clamp((q[r+1][c+1]-csc[r+1][c+1])-q[r][c]))  (0 if r==255||c==255)
//   wn=exp2(...(r+1,c)...) (0 if r==255);  wr=exp2(...(r,c+1)...) (0 if c==255)
// ---------------------------------------------------------------------------
__global__ void __launch_bounds__(256) weights_kernel(const float* __restrict__ qR,
                                                      const float* __restrict__ costR,
                                                      float* __restrict__ WD,
                                                      float* __restrict__ WN,
                                                      float* __restrict__ WR) {
  int b = blockIdx.x >> 8, r = blockIdx.x & 255, c = threadIdx.x;
  const float* q0 = qR + (size_t)b * 65536 + (size_t)r * 256;
  const float* q1 = q0 + (r < 255 ? 256 : 0);
  const float* c0 = costR + (size_t)b * 65536 + (size_t)r * 256;
  const float* c1 = c0 + (r < 255 ? 256 : 0);
  int cp = min(c + 1, 255);
  float qc = q0[c];
  float qn = q1[c], qr = q0[cp], qd = q1[cp];
  float cn = c1[c], cr = c0[cp], cd = c1[cp];
  const float CL = 50.0f * 1.4426950408889634f;
  float ad = fminf(fmaxf((qd - cd) - qc, -CL), CL);
  float an = fminf(fmaxf((qn - cn) - qc, -CL), CL);
  float ar = fminf(fmaxf((qr - cr) - qc, -CL), CL);
  bool rm = (r < 255), cm = (c < 255);
  size_t o = (size_t)b * 65536 + (size_t)r * 256 + c;
  WD[o] = (rm && cm) ? EXP2F(ad) : 0.0f;
  WN[o] = rm ? EXP2F(an) : 0.0f;
  WR[o] = cm ? EXP2F(ar) : 0.0f;
}

// ---------------------------------------------------------------------------
// Kernel 4: backward recurrence -- mirrored 4-wave relay.  Wave 3 leads.
//   E[r][c] = E[r+1][c+1]*wd + E[r+1][c]*wn + E[r][c+1]*wr,  E[255][255]=1.
// Lane l wave w (row r=64w+l) processes group G (cols 4G..4G+3, right->left)
// at slot s = (63-G)+(63-l)+64(3-w).  Row r+1: shfl_down, or LDS ring from
// wave w+1's lane0 (written one slot earlier).  E written ROW-MAJOR directly
// into the alignment output -- no transpose kernel.
// ---------------------------------------------------------------------------
__global__ void __launch_bounds__(256, 1) bwd_kernel(const float* __restrict__ WD,
                                                     const float* __restrict__ WN,
                                                     const float* __restrict__ WR,
                                                     float* __restrict__ out) {
  int b = blockIdx.x;
  int t = threadIdx.x, w = t >> 6, l = t & 63;
  int r = 64 * w + l;
  const float* wdrow = WD + (size_t)b * 65536 + (size_t)r * 256;
  const float* wnrow = WN + (size_t)b * 65536 + (size_t)r * 256;
  const float* wrrow = WR + (size_t)b * 65536 + (size_t)r * 256;
  float* orow = out + (size_t)b * 65536 + (size_t)r * 256;
  __shared__ float ring[3][64][4];   // interface: wave w+1 lane0 -> wave w lane63
  float rprev = 0.0f, dcar = 0.0f;   // col 4G+4 of my row / row r+1
  float o0 = 0.0f, o1 = 0.0f, o2 = 0.0f, o3 = 0.0f;
  int base = 64 * (3 - w), myoff = base + (63 - l);
  float D0[4], N0[4], R0[4], D1[4], N1[4], R1[4], D2[4], N2[4], R2[4];

  auto loadW = [&](int s, float* D, float* N, float* Rw) {
    if ((unsigned)(s - base) > 126u) return;
    int gg = s - myoff;
    gg = gg < 0 ? 0 : (gg > 63 ? 63 : gg);
    int G = 63 - gg;
    float4 vd = *(const float4*)(wdrow + 4 * G);
    float4 vn = *(const float4*)(wnrow + 4 * G);
    float4 vr = *(const float4*)(wrrow + 4 * G);
    D[0]=vd.x; D[1]=vd.y; D[2]=vd.z; D[3]=vd.w;
    N[0]=vn.x; N[1]=vn.y; N[2]=vn.z; N[3]=vn.w;
    Rw[0]=vr.x; Rw[1]=vr.y; Rw[2]=vr.z; Rw[3]=vr.w;
  };
  auto body = [&](int s, const float* wd, const float* wn, const float* wr) {
    if ((unsigned)(s - base) <= 126u) {
      int gg = s - myoff;
      bool act = (unsigned)gg <= 63u;
      int ggc = gg < 0 ? 0 : (gg > 63 ? 63 : gg);
      int G = 63 - ggc;
      float d0 = __shfl_down(o0, 1), d1 = __shfl_down(o1, 1),
            d2 = __shfl_down(o2, 1), d3 = __shfl_down(o3, 1);
      if (l == 63) {
        if (w == 3) { d0 = d1 = d2 = d3 = 0.0f; }
        else {
          float4 rv = *(const float4*)ring[w][G];
          d0 = rv.x; d1 = rv.y; d2 = rv.z; d3 = rv.w;
        }
      }
      float v3 = dcar * wd[3] + d3 * wn[3] + rprev * wr[3];
      if (w == 3 && l == 63 && G == 63) v3 = 1.0f;   // seed E[255][255]
      float v2 = d3 * wd[2] + d2 * wn[2] + v3 * wr[2];
      float v1 = d2 * wd[1] + d1 * wn[1] + v2 * wr[1];
      float v0 = d1 * wd[0] + d0 * wn[0] + v1 * wr[0];
      if (act) {
        float4 st = {v0, v1, v2, v3};
        *(float4*)(orow + 4 * G) = st;
        o0 = v0; o1 = v1; o2 = v2; o3 = v3;
        rprev = v0; dcar = d0;
        if (l == 0 && w > 0) *(float4*)ring[w - 1][G] = st;
      }
    }
    lds_barrier();
  };

  loadW(0, D0, N0, R0); loadW(1, D1, N1, R1); loadW(2, D2, N2, R2);
  for (int it = 0; it < 107; ++it) {   // 321 slots; last live slot = 318
    int s = it * 3;
    body(s + 0, D0, N0, R0); loadW(s + 3, D0, N0, R0);
    body(s + 1, D1, N1, R1); loadW(s + 4, D1, N1, R1);
    body(s + 2, D2, N2, R2); loadW(s + 5, D2, N2, R2);
  }
}

// ---------------------------------------------------------------------------
// Workspace (floats), ~10.5 MB (all row-major, 65536 per batch):
//   rnx @ 0 (2048) | rny @ 2048 (2048) | costR @ 4096 | qR | WD | WN | WR
// Alignment (E) goes straight into d_out from bwd_kernel.
// d_out: alignment [0 .. 524287], distance [524288 .. 524295].
// ---------------------------------------------------------------------------
extern "C" void kernel_launch(void* const* d_in, const int* in_sizes, int n_in,
                              void* d_out, int out_size, void* d_ws, size_t ws_size,
                              hipStream_t stream) {
  const float* x = (const float*)d_in[0];
  const float* y = (const float*)d_in[1];
  const float* gamma = (const float*)d_in[2];
  float* out = (float*)d_out;
  float* ws = (float*)d_ws;

  const size_t MAT = (size_t)8 * 65536;
  float* rnx   = ws;
  float* rny   = ws + 2048;
  float* costR = ws + 4096;
  float* qR    = costR + MAT;
  float* WDp   = qR    + MAT;
  float* WNp   = WDp   + MAT;
  float* WRp   = WNp   + MAT;

  norms_kernel<<<1024, 256, 0, stream>>>(x, y, rnx, rny);
  cost_gemm<<<dim3(4, 4, 8), 256, 0, stream>>>(x, y, rnx, rny, gamma, costR);
  fwd_kernel<<<8, 256, 0, stream>>>(costR, gamma, qR, out + 524288);
  weights_kernel<<<2048, 256, 0, stream>>>(qR, costR, WDp, WNp, WRp);
  bwd_kernel<<<8, 256, 0, stream>>>(WDp, WNp, WRp, out);
}

// Round 10
// 211.302 us; speedup vs baseline: 2.3489x; 2.3489x over previous
//
#include <hip/hip_runtime.h>

// Problem constants: B=8, M=N=256, D=512
#define INFV 1.0e8f

// Raw HW transcendentals: v_exp_f32 is 2^x, v_log_f32 is log2(x).
#define EXP2F(x) __builtin_amdgcn_exp2f(x)
#define LOG2F(x) __builtin_amdgcn_logf(x)
#define MED3F(a,b,c) __builtin_amdgcn_fmed3f(a,b,c)

__device__ __forceinline__ void ld4(float d[4], const float* p) {
  float4 v = *(const float4*)p;
  d[0] = v.x; d[1] = v.y; d[2] = v.z; d[3] = v.w;
}

// softmin in the q = R*(log2e/gv) domain; one exp2 arg is exactly 0:
//   softmin(a,b,c) = mn - log2(1 + exp2(mn-med) + exp2(mn-max))
__device__ __forceinline__ float softmin3(float a, float b, float c) {
  float mn = fminf(fminf(a, b), c);
  float md = MED3F(a, b, c);
  float mx = fmaxf(fmaxf(a, b), c);
  return mn - LOG2F(1.0f + EXP2F(mn - md) + EXP2F(mn - mx));
}

// ---------------------------------------------------------------------------
// Kernel 1: inverse row norms.  rn = 1 / max(||row||, 1e-8)
// ---------------------------------------------------------------------------
__global__ void __launch_bounds__(256) norms_kernel(const float* __restrict__ x,
                                                    const float* __restrict__ y,
                                                    float* __restrict__ rnx,
                                                    float* __restrict__ rny) {
  int g = blockIdx.x * 4 + (threadIdx.x >> 6);
  int lane = threadIdx.x & 63;
  const float* src; float* dst; int row;
  if (g < 2048) { src = x; dst = rnx; row = g; }
  else          { src = y; dst = rny; row = g - 2048; }
  const float* p = src + (size_t)row * 512;
  float4 v0 = *(const float4*)(p + lane * 4);
  float4 v1 = *(const float4*)(p + 256 + lane * 4);
  float s = v0.x*v0.x + v0.y*v0.y + v0.z*v0.z + v0.w*v0.w
          + v1.x*v1.x + v1.y*v1.y + v1.z*v1.z + v1.w*v1.w;
#pragma unroll
  for (int o = 32; o > 0; o >>= 1) s += __shfl_xor(s, o, 64);
  if (lane == 0) dst[row] = 1.0f / fmaxf(sqrtf(s), 1e-8f);
}

// ---------------------------------------------------------------------------
// Kernel 2: cost GEMM -> ROW-MAJOR costR[b][m][n], PRE-SCALED by ig2=log2e/gv.
// ---------------------------------------------------------------------------
__global__ void __launch_bounds__(256) cost_gemm(const float* __restrict__ x,
                                                 const float* __restrict__ y,
                                                 const float* __restrict__ rnx,
                                                 const float* __restrict__ rny,
                                                 const float* __restrict__ gamma,
                                                 float* __restrict__ costR) {
  int b = blockIdx.z, mt = blockIdx.y, nt = blockIdx.x;
  int m0 = mt * 64, n0 = nt * 64;
  __shared__ float Xs[16][68];
  __shared__ float Ys[16][68];
  int tid = threadIdx.x;
  int row = tid >> 2, cq = tid & 3;
  int tx = tid & 15, ty = tid >> 4;
  const float* xb = x + ((size_t)b * 256 + m0) * 512;
  const float* yb = y + ((size_t)b * 256 + n0) * 512;
  float acc[4][4] = {};
  for (int k0 = 0; k0 < 512; k0 += 16) {
    float4 xv = *(const float4*)(xb + (size_t)row * 512 + k0 + cq * 4);
    float4 yv = *(const float4*)(yb + (size_t)row * 512 + k0 + cq * 4);
    __syncthreads();
    Xs[cq*4+0][row] = xv.x; Xs[cq*4+1][row] = xv.y;
    Xs[cq*4+2][row] = xv.z; Xs[cq*4+3][row] = xv.w;
    Ys[cq*4+0][row] = yv.x; Ys[cq*4+1][row] = yv.y;
    Ys[cq*4+2][row] = yv.z; Ys[cq*4+3][row] = yv.w;
    __syncthreads();
#pragma unroll
    for (int kk = 0; kk < 16; ++kk) {
      float4 av = *(const float4*)(&Xs[kk][ty * 4]);
      float4 bv = *(const float4*)(&Ys[kk][tx * 4]);
      float ar[4] = {av.x, av.y, av.z, av.w};
      float br[4] = {bv.x, bv.y, bv.z, bv.w};
#pragma unroll
      for (int r = 0; r < 4; ++r)
#pragma unroll
        for (int c = 0; c < 4; ++c)
          acc[r][c] += ar[r] * br[c];
    }
  }
  float gv = fmaxf(fabsf(gamma[0]), 1e-4f);
  float ig2 = 1.4426950408889634f / gv;
  float rx[4], ry[4];
#pragma unroll
  for (int r = 0; r < 4; ++r) rx[r] = rnx[b * 256 + m0 + ty * 4 + r];
#pragma unroll
  for (int c = 0; c < 4; ++c) ry[c] = rny[b * 256 + n0 + tx * 4 + c];
  float* cbb = costR + (size_t)b * 65536;
#pragma unroll
  for (int r = 0; r < 4; ++r) {
    int m = m0 + ty * 4 + r;
    float4 st = {(1.0f - acc[r][0] * rx[r] * ry[0]) * ig2,
                 (1.0f - acc[r][1] * rx[r] * ry[1]) * ig2,
                 (1.0f - acc[r][2] * rx[r] * ry[2]) * ig2,
                 (1.0f - acc[r][3] * rx[r] * ry[3]) * ig2};
    *(float4*)(cbb + (size_t)m * 256 + n0 + tx * 4) = st;
  }
}

// ---------------------------------------------------------------------------
// Kernel 3: forward soft-DTW, ROW-STRIP: one wave per batch, lane l owns
// COLUMNS 4l..4l+3 and walks rows top->bottom, skewed (lane l does row r at
// slot s = r + l).  Per slot: ONE shfl_up (lane l-1's col 4l-1 value of the
// same row), a 4-cell left-to-right chain, one coalesced float4 cost load
// (3-deep FIFO), one coalesced float4 q store.  319 slots; no LDS/barriers.
// ---------------------------------------------------------------------------
__global__ void __launch_bounds__(64, 1) fwd_kernel(const float* __restrict__ costR,
                                                    const float* __restrict__ gamma,
                                                    float* __restrict__ qR,
                                                    float* __restrict__ dist_out) {
  int b = blockIdx.x, l = threadIdx.x;
  float gv = fmaxf(fabsf(gamma[0]), 1e-4f);
  float gl = gv * 0.6931471805599453f;      // R = q * gl
  const float* cb = costR + (size_t)b * 65536 + 4 * l;
  float* qb = qR + (size_t)b * 65536 + 4 * l;
  float ub0 = INFV, ub1 = INFV, ub2 = INFV, ub3 = INFV;  // q[r-1][4l+k]
  float o3 = INFV;                           // my last row's col 4l+3
  float ucar = (l == 0) ? 0.0f : INFV;       // q[r-1][4l-1]; (0,0) diag seed
  float A0[4], A1[4], A2[4];
  auto loadC = [&](int s, float* buf) {
    int r = s - l; r = r < 0 ? 0 : (r > 255 ? 255 : r);
    ld4(buf, cb + (size_t)r * 256);
  };
  auto body = [&](int s, const float* cc) {
    int r = s - l;
    bool act = (unsigned)r <= 255u;
    float li = __shfl_up(o3, 1);     // q[r][4l-1] (lane l-1, one slot behind)
    if (l == 0) li = INFV;
    float v0 = cc[0] + softmin3(ub0, li, ucar);
    float v1 = cc[1] + softmin3(ub1, v0, ub0);
    float v2 = cc[2] + softmin3(ub2, v1, ub1);
    float v3 = cc[3] + softmin3(ub3, v2, ub2);
    if (act) {
      float4 st = {v0, v1, v2, v3};
      *(float4*)(qb + (size_t)r * 256) = st;
      ub0 = v0; ub1 = v1; ub2 = v2; ub3 = v3;
      o3 = v3; ucar = li;
      if (l == 63 && r == 255) dist_out[b] = v3 * gl;
    }
  };
  loadC(0, A0); loadC(1, A1); loadC(2, A2);
  for (int it = 0; it < 107; ++it) {   // 321 slots; last live slot = 318
    int s = it * 3;
    body(s + 0, A0); loadC(s + 3, A0);
    body(s + 1, A1); loadC(s + 4, A1);
    body(s + 2, A2); loadC(s + 5, A2);
  }
}

// ---------------------------------------------------------------------------
// Kernel 3.5: backward weights, PACKED: record[(b*256+r)*64+l] = 16 floats
// (wd[0..3], wn[0..3], wr[0..3], pad) = one aligned 64 B line per (row,lane).
// Boundary masking folded in (w=0).  Reads/writes fully coalesced.
// ---------------------------------------------------------------------------
__global__ void __launch_bounds__(256) weights_kernel(const float* __restrict__ qR,
                                                      const float* __restrict__ costR,
                                                      float* __restrict__ W3) {
  int tid = blockIdx.x * 256 + threadIdx.x;   // = ((b*256 + r)*64 + l)
  int l = tid & 63;
  int r = (tid >> 6) & 255;
  int b = tid >> 14;
  const float* qb = qR + (size_t)b * 65536;
  const float* cbb = costR + (size_t)b * 65536;
  int rp = min(r + 1, 255);
  int c0i = 4 * l;
  int c4 = min(c0i + 4, 255);
  float q0a[5], q1a[5], c0a[5], c1a[5];
  ld4(q0a, qb + (size_t)r * 256 + c0i);  q0a[4] = qb[(size_t)r * 256 + c4];
  ld4(q1a, qb + (size_t)rp * 256 + c0i); q1a[4] = qb[(size_t)rp * 256 + c4];
  ld4(c0a, cbb + (size_t)r * 256 + c0i);  c0a[4] = cbb[(size_t)r * 256 + c4];
  ld4(c1a, cbb + (size_t)rp * 256 + c0i); c1a[4] = cbb[(size_t)rp * 256 + c4];
  const float CL = 50.0f * 1.4426950408889634f;
  bool rm = (r < 255);
  float w[16];
#pragma unroll
  for (int k = 0; k < 4; ++k) {
    bool cm = (c0i + k < 255);
    float ad = fminf(fmaxf((q1a[k+1] - c1a[k+1]) - q0a[k], -CL), CL);
    float an = fminf(fmaxf((q1a[k]   - c1a[k])   - q0a[k], -CL), CL);
    float ar = fminf(fmaxf((q0a[k+1] - c0a[k+1]) - q0a[k], -CL), CL);
    w[k]      = (rm && cm) ? EXP2F(ad) : 0.0f;
    w[4 + k]  = rm ? EXP2F(an) : 0.0f;
    w[8 + k]  = cm ? EXP2F(ar) : 0.0f;
    w[12 + k] = 0.0f;
  }
  float* wp = W3 + (size_t)tid * 16;
#pragma unroll
  for (int j = 0; j < 4; ++j) *(float4*)(wp + 4 * j) = *(float4*)(w + 4 * j);
}

// ---------------------------------------------------------------------------
// Kernel 4: backward recurrence, ROW-STRIP mirrored: lane l owns cols
// 4l..4l+3, walks rows bottom->top; lane l does row r at slot s = 318-r-l
// (lane 63 leads).  Per slot: ONE shfl_down (lane l+1's col 4l+4 value of
// the same row), 12 FMAs, one 64 B packed-weight record via a 6-DEEP FIFO
// (24 outstanding dwordx4/wave), one float4 E store DIRECTLY to d_out.
//   E[r][c] = E[r+1][c+1]*wd + E[r+1][c]*wn + E[r][c+1]*wr,  E[255][255]=1.
// ---------------------------------------------------------------------------
__global__ void __launch_bounds__(64, 1) bwd_kernel(const float* __restrict__ W3,
                                                    float* __restrict__ out) {
  int b = blockIdx.x, l = threadIdx.x;
  const float* wb = W3 + ((size_t)b * 16384 + l) * 16;   // + r*1024
  float* ob = out + (size_t)b * 65536 + 4 * l;
  float db0 = 0.f, db1 = 0.f, db2 = 0.f, db3 = 0.f;  // E[r+1][4l+k]
  float o0 = 0.f;       // my last row's col 4l value
  float dcar = 0.f;     // E[r+1][4l+4]
  float F0[16], F1[16], F2[16], F3[16], F4[16], F5[16];
  auto loadW = [&](int s, float* buf) {
    int r = 318 - s - l; r = r < 0 ? 0 : (r > 255 ? 255 : r);
    const float* p = wb + (size_t)r * 1024;
    ld4(buf, p); ld4(buf + 4, p + 4); ld4(buf + 8, p + 8); ld4(buf + 12, p + 12);
  };
  auto body = [&](int s, const float* w) {
    int r = 318 - s - l;
    bool act = (unsigned)r <= 255u;
    float ri = __shfl_down(o0, 1);   // E[r][4l+4] (lane l+1, one slot behind)
    if (l == 63) ri = 0.0f;
    float v3 = w[3] * dcar + w[7] * db3 + w[11] * ri;
    if (l == 63 && r == 255) v3 = 1.0f;     // seed E[255][255]
    float v2 = w[2] * db3 + w[6] * db2 + w[10] * v3;
    float v1 = w[1] * db2 + w[5] * db1 + w[9]  * v2;
    float v0 = w[0] * db1 + w[4] * db0 + w[8]  * v1;
    if (act) {
      float4 st = {v0, v1, v2, v3};
      *(float4*)(ob + (size_t)r * 256) = st;
      db0 = v0; db1 = v1; db2 = v2; db3 = v3;
      o0 = v0; dcar = ri;
    }
  };
  loadW(0, F0); loadW(1, F1); loadW(2, F2);
  loadW(3, F3); loadW(4, F4); loadW(5, F5);
  for (int it = 0; it < 54; ++it) {   // 324 slots; last live slot = 318
    int s = it * 6;
    body(s + 0, F0); loadW(s + 6,  F0);
    body(s + 1, F1); loadW(s + 7,  F1);
    body(s + 2, F2); loadW(s + 8,  F2);
    body(s + 3, F3); loadW(s + 9,  F3);
    body(s + 4, F4); loadW(s + 10, F4);
    body(s + 5, F5); loadW(s + 11, F5);
  }
}

// ---------------------------------------------------------------------------
// Workspace (floats), ~12.6 MB:
//   rnx @ 0 (2048) | rny @ 2048 (2048)
//   costR @ 4096        (8*65536, row-major, pre-scaled by ig2)
//   qR    @ +524288     (8*65536, row-major)
//   W3    @ +524288     (8*256*64*16 = 2,097,152: packed 64 B weight records)
// Alignment (E) goes straight into d_out from bwd_kernel.
// d_out: alignment [0 .. 524287], distance [524288 .. 524295].
// ---------------------------------------------------------------------------
extern "C" void kernel_launch(void* const* d_in, const int* in_sizes, int n_in,
                              void* d_out, int out_size, void* d_ws, size_t ws_size,
                              hipStream_t stream) {
  const float* x = (const float*)d_in[0];
  const float* y = (const float*)d_in[1];
  const float* gamma = (const float*)d_in[2];
  float* out = (float*)d_out;
  float* ws = (float*)d_ws;

  const size_t MAT = (size_t)8 * 65536;
  float* rnx   = ws;
  float* rny   = ws + 2048;
  float* costR = ws + 4096;
  float* qR    = costR + MAT;
  float* W3    = qR + MAT;

  norms_kernel<<<1024, 256, 0, stream>>>(x, y, rnx, rny);
  cost_gemm<<<dim3(4, 4, 8), 256, 0, stream>>>(x, y, rnx, rny, gamma, costR);
  fwd_kernel<<<8, 64, 0, stream>>>(costR, gamma, qR, out + 524288);
  weights_kernel<<<512, 256, 0, stream>>>(qR, costR, W3);
  bwd_kernel<<<8, 64, 0, stream>>>(W3, out);
}